// Round 9
// baseline (157.190 us; speedup 1.0000x reference)
//
#include <hip/hip_runtime.h>
#include <hip/hip_bf16.h>

#define DEV __device__ __forceinline__

typedef __attribute__((ext_vector_type(8))) short bf16x8;
typedef __attribute__((ext_vector_type(4))) float f32x4;

constexpr int Bq = 16, Lq = 2048, Dq = 128;
constexpr int RZ = 2 * Dq;            // 256
constexpr float L2E = 1.4426950408889634f;   // log2(e)

DEV float exp2f_hw(float x) { return __builtin_amdgcn_exp2f(x); }  // v_exp_f32

DEV unsigned short f2bf(float f) {
    union { __hip_bfloat16 h; unsigned short u; } v;
    v.h = __float2bfloat16(f);
    return v.u;
}
DEV float bfu_lo(int u) { return __uint_as_float((unsigned)u << 16); }
DEV float bfu_hi(int u) { return __uint_as_float((unsigned)u & 0xffff0000u); }

// sigmoid(x) given y = x*log2e :  1/(1+2^-y)
DEV float sigm2(float y) { return __builtin_amdgcn_rcpf(1.f + exp2f_hw(-y)); }
// tanh(v) given y = 2v*log2e :  1 - 2/(2^y + 1)
DEV float tanh2(float y) {
    float e = exp2f_hw(y);
    return fmaf(-2.f, __builtin_amdgcn_rcpf(e + 1.f), 1.f);
}

DEV bf16x8 pack8s(float4 a, float4 b, float s) {
    bf16x8 r;
    r[0] = (short)f2bf(a.x * s); r[1] = (short)f2bf(a.y * s);
    r[2] = (short)f2bf(a.z * s); r[3] = (short)f2bf(a.w * s);
    r[4] = (short)f2bf(b.x * s); r[5] = (short)f2bf(b.y * s);
    r[6] = (short)f2bf(b.z * s); r[7] = (short)f2bf(b.w * s);
    return r;
}
DEV int2 packbf4(float a, float b, float c, float d) {
    int2 r;
    r.x = (int)(((unsigned)f2bf(b) << 16) | (unsigned)f2bf(a));
    r.y = (int)(((unsigned)f2bf(d) << 16) | (unsigned)f2bf(c));
    return r;
}

// ---------------------------------------------------------------------------
// Fused local GRU.  Block = 32 windows (grid 1024), 8 waves.
// Phase 0: stage x rows [l0-7, l0+32) as bf16 swizzled B-tile (zeros outside).
// Phase 1: project gates locally: xpt[48 rows][384] = (x@W_ih^T + bias)*scale
//          (rows with zero x automatically become the bias pad rows).
// Phase 2: round-7 recurrence; gate inputs ds_read at step top, consumed
//          after MFMA (ar/az 0-init); h bf16 republished to dbuf hls,
//          1 barrier/step.  afr registers reused W_ih -> W_hh.
// LDS 52KB, (512,2) -> no spills, 2 blocks/CU.
// ---------------------------------------------------------------------------
__global__ __launch_bounds__(512, 2) void k_fused(
    const float* __restrict__ x, const float* __restrict__ W_ih,
    const float* __restrict__ W_hh, const float* __restrict__ b_ih,
    const float* __restrict__ b_hh, float* __restrict__ out)
{
    __shared__ __attribute__((aligned(16))) unsigned char xpt[48 * 768];  // 36864B gate tile
    __shared__ __attribute__((aligned(16))) unsigned char buf2[16384];    // xls (12KB) then hls dbuf

    const int tid = threadIdx.x;
    const int lane = tid & 63, w = tid >> 6;
    const int l15 = lane & 15, l4 = lane >> 4;
    const int b = blockIdx.x >> 6;
    const int l0 = (blockIdx.x & 63) << 5;

    // ---- phase 0: stage x rows -> bf16 swizzled LDS (buf2), zero-padded ----
    {
        const float4* xb = (const float4*)(x + (size_t)b * Lq * Dq);
#pragma unroll
        for (int it = 0; it < 3; ++it) {
            int c = it * 512 + tid;            // [0,1536): 48 rows x 32 float4
            int row = c >> 5, col = c & 31;
            int l = l0 - 7 + row;
            float4 v = make_float4(0.f, 0.f, 0.f, 0.f);
            if (row < 39 && l >= 0) v = xb[(size_t)l * 32 + col];
            int dst = row * 256 + ((col << 3) ^ ((row & 7) << 4));
            *(int2*)(buf2 + dst) = packbf4(v.x, v.y, v.z, v.w);
        }
    }

    // A-fragments for phase 1: W_ih rows [48w, 48w+48)
    bf16x8 afr[3][4];
#pragma unroll
    for (int mt = 0; mt < 3; ++mt)
#pragma unroll
        for (int kc = 0; kc < 4; ++kc) {
            int row = 48 * w + 16 * mt + l15;
            const float* p = W_ih + row * Dq + 32 * kc + 8 * l4;
            afr[mt][kc] = pack8s(*(const float4*)p, *(const float4*)(p + 4), 1.f);
        }
    float fs[3];
    f32x4 bias[3];
#pragma unroll
    for (int mt = 0; mt < 3; ++mt) {
        int rbase = 48 * w + 16 * mt + 4 * l4;
        fs[mt] = (rbase < RZ) ? L2E : 2.f * L2E;
#pragma unroll
        for (int r = 0; r < 4; ++r) {
            int row = rbase + r;
            bias[mt][r] = (b_ih[row] + (row < RZ ? b_hh[row] : 0.f)) * fs[mt];
        }
    }
    __syncthreads();

    // ---- phase 1: projection GEMM -> xpt (scaled + bias, swizzled) ----
    {
        f32x4 acc[3][3];
#pragma unroll
        for (int mt = 0; mt < 3; ++mt)
#pragma unroll
            for (int nt = 0; nt < 3; ++nt) {
                acc[mt][nt][0] = 0.f; acc[mt][nt][1] = 0.f;
                acc[mt][nt][2] = 0.f; acc[mt][nt][3] = 0.f;
            }
#pragma unroll
        for (int kc = 0; kc < 4; ++kc) {
            bf16x8 bfr[3];
#pragma unroll
            for (int nt = 0; nt < 3; ++nt) {
                int row = 16 * nt + l15;
                int off = row * 256 + ((64 * kc + 16 * l4) ^ ((row & 7) << 4));
                bfr[nt] = *(const bf16x8*)(buf2 + off);
            }
#pragma unroll
            for (int nt = 0; nt < 3; ++nt)
#pragma unroll
                for (int mt = 0; mt < 3; ++mt)
                    acc[mt][nt] = __builtin_amdgcn_mfma_f32_16x16x32_bf16(
                        afr[mt][kc], bfr[nt], acc[mt][nt], 0, 0, 0);
        }
#pragma unroll
        for (int mt = 0; mt < 3; ++mt)
#pragma unroll
            for (int nt = 0; nt < 3; ++nt) {
                int lrow = 16 * nt + l15;
                int g = 48 * w + 16 * mt + 4 * l4;
                int sw = (lrow & 7) << 3;
                int2 pk = packbf4(fmaf(acc[mt][nt][0], fs[mt], bias[mt][0]),
                                  fmaf(acc[mt][nt][1], fs[mt], bias[mt][1]),
                                  fmaf(acc[mt][nt][2], fs[mt], bias[mt][2]),
                                  fmaf(acc[mt][nt][3], fs[mt], bias[mt][3]));
                *(int2*)(xpt + lrow * 768 + ((g ^ sw) << 1)) = pk;
            }
    }
    __syncthreads();

    // ---- reload afr with scaled W_hh; recurrence biases ----
#pragma unroll
    for (int g = 0; g < 3; ++g) {
        float fg = (g < 2) ? L2E : 2.f * L2E;
#pragma unroll
        for (int kc = 0; kc < 4; ++kc) {
            int row = 128 * g + 16 * w + l15;
            const float* p = W_hh + row * Dq + 32 * kc + 8 * l4;
            afr[g][kc] = pack8s(*(const float4*)p, *(const float4*)(p + 4), fg);
        }
    }
    const int u0 = 16 * w + 4 * l4;
    f32x4 bhn4;
#pragma unroll
    for (int r = 0; r < 4; ++r) bhn4[r] = b_hh[RZ + u0 + r] * (2.f * L2E);

    f32x4 h[2];

    // ---- t = 0 (h0 == 0: gates from xpt only) ----
#pragma unroll
    for (int nt = 0; nt < 2; ++nt) {
        int tr = 16 * nt + l15;
        int s = (tr & 7) << 3;
        const unsigned char* rowp = xpt + tr * 768;
        int2 qr = *(const int2*)(rowp + ((u0 ^ s) << 1));
        int2 qz = *(const int2*)(rowp + (((Dq + u0) ^ s) << 1));
        int2 qn = *(const int2*)(rowp + (((RZ + u0) ^ s) << 1));
        float xr[4] = {bfu_lo(qr.x), bfu_hi(qr.x), bfu_lo(qr.y), bfu_hi(qr.y)};
        float xz[4] = {bfu_lo(qz.x), bfu_hi(qz.x), bfu_lo(qz.y), bfu_hi(qz.y)};
        float xn[4] = {bfu_lo(qn.x), bfu_hi(qn.x), bfu_lo(qn.y), bfu_hi(qn.y)};
#pragma unroll
        for (int r = 0; r < 4; ++r) {
            float rv = sigm2(xr[r]);
            float zv = sigm2(xz[r]);
            float nv = tanh2(fmaf(rv, bhn4[r], xn[r]));
            h[nt][r] = nv - zv * nv;   // h_prev = 0
        }
    }
#pragma unroll
    for (int nt = 0; nt < 2; ++nt) {
        int win = 16 * nt + l15;
        int off = win * 256 + ((2 * u0) ^ ((win & 7) << 4));   // hls buffer 0
        *(int2*)(buf2 + off) = packbf4(h[nt][0], h[nt][1], h[nt][2], h[nt][3]);
    }
    __syncthreads();

    // ---- t = 1..7 : one barrier per step; gate reads at top, used post-MFMA ----
    for (int t = 1; t < 8; ++t) {
        const int rdo = ((t - 1) & 1) << 13;
        const int wro = (t & 1) << 13;

        int2 qr_s[2], qz_s[2], qn_s[2];
#pragma unroll
        for (int nt = 0; nt < 2; ++nt) {
            int tr = 16 * nt + l15 + t;
            int s = (tr & 7) << 3;
            const unsigned char* rowp = xpt + tr * 768;
            qr_s[nt] = *(const int2*)(rowp + ((u0 ^ s) << 1));
            qz_s[nt] = *(const int2*)(rowp + (((Dq + u0) ^ s) << 1));
            qn_s[nt] = *(const int2*)(rowp + (((RZ + u0) ^ s) << 1));
        }

        f32x4 ar[2], az[2], an[2];
#pragma unroll
        for (int nt = 0; nt < 2; ++nt) {
            ar[nt][0] = 0.f; ar[nt][1] = 0.f; ar[nt][2] = 0.f; ar[nt][3] = 0.f;
            az[nt] = ar[nt];
            an[nt] = bhn4;
        }
#pragma unroll
        for (int kc = 0; kc < 4; ++kc) {
            bf16x8 bfr[2];
#pragma unroll
            for (int nt = 0; nt < 2; ++nt) {
                int win = 16 * nt + l15;
                int off = rdo + win * 256 + ((64 * kc + 16 * l4) ^ ((win & 7) << 4));
                bfr[nt] = *(const bf16x8*)(buf2 + off);
            }
#pragma unroll
            for (int nt = 0; nt < 2; ++nt) {
                ar[nt] = __builtin_amdgcn_mfma_f32_16x16x32_bf16(afr[0][kc], bfr[nt], ar[nt], 0, 0, 0);
                az[nt] = __builtin_amdgcn_mfma_f32_16x16x32_bf16(afr[1][kc], bfr[nt], az[nt], 0, 0, 0);
                an[nt] = __builtin_amdgcn_mfma_f32_16x16x32_bf16(afr[2][kc], bfr[nt], an[nt], 0, 0, 0);
            }
        }
#pragma unroll
        for (int nt = 0; nt < 2; ++nt) {
            float xr[4] = {bfu_lo(qr_s[nt].x), bfu_hi(qr_s[nt].x),
                           bfu_lo(qr_s[nt].y), bfu_hi(qr_s[nt].y)};
            float xz[4] = {bfu_lo(qz_s[nt].x), bfu_hi(qz_s[nt].x),
                           bfu_lo(qz_s[nt].y), bfu_hi(qz_s[nt].y)};
            float xn[4] = {bfu_lo(qn_s[nt].x), bfu_hi(qn_s[nt].x),
                           bfu_lo(qn_s[nt].y), bfu_hi(qn_s[nt].y)};
#pragma unroll
            for (int r = 0; r < 4; ++r) {
                float rv = sigm2(ar[nt][r] + xr[r]);
                float zv = sigm2(az[nt][r] + xz[r]);
                float nv = tanh2(fmaf(rv, an[nt][r], xn[r]));
                h[nt][r] = nv + zv * (h[nt][r] - nv);
            }
        }
        if (t < 7) {
#pragma unroll
            for (int nt = 0; nt < 2; ++nt) {
                int win = 16 * nt + l15;
                int off = wro + win * 256 + ((2 * u0) ^ ((win & 7) << 4));
                *(int2*)(buf2 + off) = packbf4(h[nt][0], h[nt][1], h[nt][2], h[nt][3]);
            }
            __syncthreads();
        }
    }

    // epilogue: h (fp32) -> out[b][l][u]
#pragma unroll
    for (int nt = 0; nt < 2; ++nt) {
        size_t idx = ((size_t)(b * Lq + l0 + 16 * nt + l15)) * Dq + u0;
        *(f32x4*)(out + idx) = h[nt];
    }
}

extern "C" void kernel_launch(void* const* d_in, const int* in_sizes, int n_in,
                              void* d_out, int out_size, void* d_ws, size_t ws_size,
                              hipStream_t stream) {
    const float* x    = (const float*)d_in[0];
    const float* W_ih = (const float*)d_in[1];
    const float* W_hh = (const float*)d_in[2];
    const float* b_ih = (const float*)d_in[3];
    const float* b_hh = (const float*)d_in[4];
    float* out = (float*)d_out;

    k_fused<<<dim3(1024), dim3(512), 0, stream>>>(x, W_ih, W_hh, b_ih, b_hh, out);
}